// Round 5
// baseline (251.973 us; speedup 1.0000x reference)
//
#include <hip/hip_runtime.h>
#include <hip/hip_fp16.h>
#include <math.h>

#define WAVE 64
#define KPAD 128   // padded K for W^T (zero-filled cols K..127)

// ---------------------------------------------------------------------------
// K1 (prep):
//  blocks [0, nTrBlk):    WT[d][c] = fp16((c<K) ? W[c][d] : 0)   (D x KPAD)
//  blocks [nTrBlk, end):  weh = fp16(we)   (grid-strided, 8 elems/thread)
// ---------------------------------------------------------------------------
__global__ __launch_bounds__(256) void k_prep(const float* __restrict__ lw,
                                              const float* __restrict__ we,
                                              __half* __restrict__ wt,
                                              __half* __restrict__ weh,
                                              int K, int D, int V, int nTrBlk) {
    int bx = blockIdx.x;
    if (bx < nTrBlk) {
        int base = (bx * 256 + (int)threadIdx.x) * 4;
        int total = D * KPAD;
        for (int i = 0; i < 4; ++i) {
            int e = base + i;
            if (e >= total) break;
            int d = e >> 7;        // / KPAD
            int c = e & (KPAD - 1);
            wt[e] = (c < K) ? __float2half(lw[(size_t)c * D + d]) : __half(0.0f);
        }
    } else {
        int cid = bx - nTrBlk;
        size_t n8 = ((size_t)V * D) >> 3;                  // groups of 8 floats
        size_t stride = ((size_t)gridDim.x - nTrBlk) * 256;
        const float4* src = (const float4*)we;
        for (size_t i = (size_t)cid * 256 + threadIdx.x; i < n8; i += stride) {
            float4 v0 = src[i * 2];
            float4 v1 = src[i * 2 + 1];
            __half2 h0 = __float22half2_rn(make_float2(v0.x, v0.y));
            __half2 h1 = __float22half2_rn(make_float2(v0.z, v0.w));
            __half2 h2 = __float22half2_rn(make_float2(v1.x, v1.y));
            __half2 h3 = __float22half2_rn(make_float2(v1.z, v1.w));
            uint4 u;
            u.x = *reinterpret_cast<const unsigned int*>(&h0);
            u.y = *reinterpret_cast<const unsigned int*>(&h1);
            u.z = *reinterpret_cast<const unsigned int*>(&h2);
            u.w = *reinterpret_cast<const unsigned int*>(&h3);
            ((uint4*)weh)[i] = u;
        }
    }
}

// ---------------------------------------------------------------------------
// K2 (fused): one block (4 waves) per bag.
//  - inline argmax over typeTensor[b]  (per-wave redundant, L1-hot)
//  - wave w owns mentions m0+w, m0+w+4, ... : mean-gather from fp16 table
//    (pair-row loads: lanes 0-31 token j, 32-63 token j+1, xor-32 merge),
//    selected score s, flash-style online (m,l,acc) update in registers
//  - LDS merge of 4 wave states -> bag_emb (256 floats)
//  - projection via fp16 W^T: wave w covers dims [64w,64w+64), lane kc owns
//    out cols {2kc,2kc+1}; partials summed in LDS, wave 0 stores.
// men_emb / sel / type_idx never touch global memory.
// ---------------------------------------------------------------------------
__global__ __launch_bounds__(256) void k_fused(const int* __restrict__ fs,
                                               const int* __restrict__ offs,
                                               const int* __restrict__ scope,
                                               const float* __restrict__ tt,
                                               const __half* __restrict__ weh,
                                               const float* __restrict__ lw,
                                               const __half* __restrict__ wt,
                                               float* __restrict__ out,
                                               int M, int T, int B, int D, int K) {
    int b    = blockIdx.x;
    int tid  = threadIdx.x;
    int wid  = tid >> 6;
    int lane = tid & 63;
    int c    = lane & 31;      // 16B-chunk (8 dims) within a row
    int hsel = lane >> 5;      // 0: even token of pair, 1: odd token

    int m0 = scope[b];
    int m1 = scope[b + 1];

    // ---- inline argmax over typeTensor row b (first-max ties) ----
    float best = -INFINITY;
    int   bi   = 0x7fffffff;
    for (int k = lane; k < K; k += WAVE) {
        float v = tt[(size_t)b * K + k];
        if (v > best) { best = v; bi = k; }
    }
    for (int off = 32; off > 0; off >>= 1) {
        float ov = __shfl_down(best, off);
        int   oi = __shfl_down(bi, off);
        if (ov > best || (ov == best && oi < bi)) { best = ov; bi = oi; }
    }
    int r = __shfl(bi, 0);

    // W row for the selected type, in gather layout (both halves identical)
    const float4* wr = (const float4*)(lw + (size_t)r * D);
    float4 u0 = wr[c * 2];
    float4 u1 = wr[c * 2 + 1];

    const float4* we16 = (const float4*)weh;   // 16B = 8 halves; 32 chunks/row

    // ---- per-wave online softmax state ----
    float mloc = -INFINITY, lloc = 0.f;
    float g0=0,g1=0,g2=0,g3=0,g4=0,g5=0,g6=0,g7=0;   // weighted bag acc

#define ACC8(q) { const __half2* hh = (const __half2*)&(q);                 \
        float2 f0=__half22float2(hh[0]), f1=__half22float2(hh[1]);          \
        float2 f2=__half22float2(hh[2]), f3=__half22float2(hh[3]);          \
        a0+=f0.x; a1+=f0.y; a2+=f1.x; a3+=f1.y;                             \
        a4+=f2.x; a5+=f2.y; a6+=f3.x; a7+=f3.y; }
#define ACC8S(q,s) { const __half2* hh = (const __half2*)&(q);              \
        float2 f0=__half22float2(hh[0]), f1=__half22float2(hh[1]);          \
        float2 f2=__half22float2(hh[2]), f3=__half22float2(hh[3]);          \
        a0+=(s)*f0.x; a1+=(s)*f0.y; a2+=(s)*f1.x; a3+=(s)*f1.y;             \
        a4+=(s)*f2.x; a5+=(s)*f2.y; a6+=(s)*f3.x; a7+=(s)*f3.y; }

    for (int m = m0 + wid; m < m1; m += 4) {
        int t0 = offs[m];
        int t1 = (m + 1 < M) ? offs[m + 1] : T;
        float a0=0,a1=0,a2=0,a3=0,a4=0,a5=0,a6=0,a7=0;

        for (int base = t0; base < t1; base += WAVE) {
            int nn = min(WAVE, t1 - base);
            int myidx = (lane < nn) ? fs[base + lane] : 0;
            int j = 0;
            for (; j + 8 <= nn; j += 8) {       // 4 pair-loads = 8 tokens
                int r0 = __shfl(myidx, j     + hsel);
                int r1 = __shfl(myidx, j + 2 + hsel);
                int r2 = __shfl(myidx, j + 4 + hsel);
                int r3 = __shfl(myidx, j + 6 + hsel);
                float4 q0 = we16[(size_t)r0 * 32 + c];
                float4 q1 = we16[(size_t)r1 * 32 + c];
                float4 q2 = we16[(size_t)r2 * 32 + c];
                float4 q3 = we16[(size_t)r3 * 32 + c];
                ACC8(q0); ACC8(q1); ACC8(q2); ACC8(q3);
            }
            for (; j < nn; j += 2) {            // pair tail (odd via s=0)
                int srcl = j + hsel;
                int rr = __shfl(myidx, (srcl < nn) ? srcl : (nn - 1));
                float s = (srcl < nn) ? 1.0f : 0.0f;
                float4 q = we16[(size_t)rr * 32 + c];
                ACC8S(q, s);
            }
        }

        // merge half-wave token streams (lane c and c+32 hold same dims)
        a0 += __shfl_xor(a0, 32); a1 += __shfl_xor(a1, 32);
        a2 += __shfl_xor(a2, 32); a3 += __shfl_xor(a3, 32);
        a4 += __shfl_xor(a4, 32); a5 += __shfl_xor(a5, 32);
        a6 += __shfl_xor(a6, 32); a7 += __shfl_xor(a7, 32);

        float inv = 1.0f / (float)(t1 - t0);
        a0*=inv; a1*=inv; a2*=inv; a3*=inv; a4*=inv; a5*=inv; a6*=inv; a7*=inv;

        // selected score s = dot(mean, W[r]) — reduce within 32 (halves dup)
        float p = a0*u0.x + a1*u0.y + a2*u0.z + a3*u0.w
                + a4*u1.x + a5*u1.y + a6*u1.z + a7*u1.w;
        for (int off = 16; off > 0; off >>= 1) p += __shfl_xor(p, off);

        // online softmax update
        float mn    = fmaxf(mloc, p);
        float alpha = expf(mloc - mn);    // 0 when mloc == -inf
        float pe    = expf(p - mn);
        lloc = lloc * alpha + pe;
        g0 = g0*alpha + pe*a0; g1 = g1*alpha + pe*a1;
        g2 = g2*alpha + pe*a2; g3 = g3*alpha + pe*a3;
        g4 = g4*alpha + pe*a4; g5 = g5*alpha + pe*a5;
        g6 = g6*alpha + pe*a6; g7 = g7*alpha + pe*a7;
        mloc = mn;
    }
#undef ACC8
#undef ACC8S

    // ---- cross-wave merge ----
    __shared__ float s_m[4], s_l[4];
    __shared__ float s_acc[4][256];
    __shared__ float s_be[256];
    __shared__ float2 s_po[4][64];

    if (hsel == 0) {
        float4* ap = (float4*)&s_acc[wid][0];
        ap[c * 2]     = make_float4(g0, g1, g2, g3);
        ap[c * 2 + 1] = make_float4(g4, g5, g6, g7);
    }
    if (lane == 0) { s_m[wid] = mloc; s_l[wid] = lloc; }
    __syncthreads();

    float gm = fmaxf(fmaxf(s_m[0], s_m[1]), fmaxf(s_m[2], s_m[3]));
    float c0 = expf(s_m[0] - gm), c1 = expf(s_m[1] - gm);
    float c2 = expf(s_m[2] - gm), c3 = expf(s_m[3] - gm);
    float lt = s_l[0]*c0 + s_l[1]*c1 + s_l[2]*c2 + s_l[3]*c3;
    float invl = 1.0f / lt;

    // thread tid owns dim tid (D == 256 == blockDim)
    s_be[tid] = (s_acc[0][tid]*c0 + s_acc[1][tid]*c1 +
                 s_acc[2][tid]*c2 + s_acc[3][tid]*c3) * invl;
    __syncthreads();

    // ---- projection: wave wid covers dims [64*wid, 64*wid+64) ----
    const __half2* wt2 = (const __half2*)wt;    // [D][KPAD/2] half2
    float2 o = make_float2(0.f, 0.f);
    int kc = lane;                              // half2 column (2kc, 2kc+1)
    const float* bep = s_be + (wid << 6);
    #pragma unroll 4
    for (int d4 = 0; d4 < 16; ++d4) {
        float4 b4 = ((const float4*)bep)[d4];   // LDS broadcast read
        int d = (wid << 6) + (d4 << 2);
        float2 w0 = __half22float2(wt2[(size_t)(d + 0) * (KPAD/2) + kc]);
        float2 w1 = __half22float2(wt2[(size_t)(d + 1) * (KPAD/2) + kc]);
        float2 w2 = __half22float2(wt2[(size_t)(d + 2) * (KPAD/2) + kc]);
        float2 w3 = __half22float2(wt2[(size_t)(d + 3) * (KPAD/2) + kc]);
        o.x += b4.x*w0.x + b4.y*w1.x + b4.z*w2.x + b4.w*w3.x;
        o.y += b4.x*w0.y + b4.y*w1.y + b4.z*w2.y + b4.w*w3.y;
    }
    s_po[wid][lane] = o;
    __syncthreads();

    if (wid == 0) {
        float2 o0 = s_po[0][lane], o1 = s_po[1][lane];
        float2 o2 = s_po[2][lane], o3 = s_po[3][lane];
        float2 oo = make_float2((o0.x+o1.x)+(o2.x+o3.x),
                                (o0.y+o1.y)+(o2.y+o3.y));
        int k0 = lane * 2;
        float* ob = out + (size_t)b * K;
        if (k0 + 1 < K) {
            ((float2*)ob)[lane] = oo;
        } else if (k0 < K) {
            ob[k0] = oo.x;
        }
    }
}

// ---------------------------------------------------------------------------
extern "C" void kernel_launch(void* const* d_in, const int* in_sizes, int n_in,
                              void* d_out, int out_size, void* d_ws, size_t ws_size,
                              hipStream_t stream) {
    const int*   feature_seq = (const int*)d_in[0];
    const int*   offset_seq  = (const int*)d_in[1];
    const int*   scope       = (const int*)d_in[2];
    const float* typeTensor  = (const float*)d_in[3];
    const float* word_emb    = (const float*)d_in[4];
    const float* linear_w    = (const float*)d_in[5];
    float* out = (float*)d_out;

    const int T = in_sizes[0];
    const int M = in_sizes[1];
    const int B = in_sizes[2] - 1;
    const int K = in_sizes[3] / B;       // 100
    const int D = in_sizes[5] / K;       // 256
    const int V = in_sizes[4] / D;       // 100000

    // workspace carve-up
    char* w = (char*)d_ws;
    auto align256 = [](size_t x) { return (x + 255) & ~(size_t)255; };
    __half* wt  = (__half*)w;  w += align256((size_t)D * KPAD * sizeof(__half));
    __half* weh = (__half*)w;  // V * D halves

    // K1: WT fp16 transpose + table fp32->fp16
    {
        int nTrBlk   = (D * KPAD + 1023) / 1024;
        int nConvBlk = 2048;
        k_prep<<<nTrBlk + nConvBlk, 256, 0, stream>>>(linear_w, word_emb,
                                                      wt, weh, K, D, V, nTrBlk);
    }
    // K2: fused mention-gather + online softmax + bag projection
    {
        k_fused<<<B, 256, 0, stream>>>(feature_seq, offset_seq, scope,
                                       typeTensor, weh, linear_w, wt, out,
                                       M, T, B, D, K);
    }
}

// Round 8
// 244.187 us; speedup vs baseline: 1.0319x; 1.0319x over previous
//
#include <hip/hip_runtime.h>
#include <hip/hip_fp16.h>
#include <math.h>

#define WAVE 64
#define KPAD 128   // padded K for W^T (zero-filled cols K..127)

typedef float        f32x4 __attribute__((ext_vector_type(4)));
typedef unsigned int u32x4 __attribute__((ext_vector_type(4)));

// ---------------------------------------------------------------------------
// K1 (prep):
//  blocks [0, nArgBlk):          type_idx[b] = argmax_k typeTensor[b*K+k]
//  blocks [nArgBlk, +nTrBlk):    WT[d][c] = fp16((c<K) ? W[c][d] : 0)
//  blocks [nArgBlk+nTrBlk, end): weh = fp16(we)  (grid-strided, NT source loads)
// ---------------------------------------------------------------------------
__global__ __launch_bounds__(256) void k_prep(const float* __restrict__ tt,
                                              const float* __restrict__ lw,
                                              const float* __restrict__ we,
                                              int* __restrict__ type_idx,
                                              __half* __restrict__ wt,
                                              __half* __restrict__ weh,
                                              int B, int K, int D, int V,
                                              int nArgBlk, int nTrBlk) {
    int bx = blockIdx.x;
    if (bx < nArgBlk) {
        int wid  = threadIdx.x >> 6;
        int lane = threadIdx.x & 63;
        int b = bx * (blockDim.x >> 6) + wid;
        if (b >= B) return;
        float best = -INFINITY;
        int   bi   = 0x7fffffff;
        for (int k = lane; k < K; k += WAVE) {
            float v = tt[(size_t)b * K + k];
            if (v > best) { best = v; bi = k; }
        }
        for (int off = 32; off > 0; off >>= 1) {
            float ov = __shfl_down(best, off);
            int   oi = __shfl_down(bi, off);
            if (ov > best || (ov == best && oi < bi)) { best = ov; bi = oi; }
        }
        if (lane == 0) type_idx[b] = bi;
    } else if (bx < nArgBlk + nTrBlk) {
        int bid = bx - nArgBlk;
        int base = (bid * 256 + (int)threadIdx.x) * 4;
        int total = D * KPAD;
        for (int i = 0; i < 4; ++i) {
            int e = base + i;
            if (e >= total) break;
            int d = e >> 7;        // / KPAD
            int c = e & (KPAD - 1);
            wt[e] = (c < K) ? __float2half(lw[(size_t)c * D + d]) : __half(0.0f);
        }
    } else {
        int cid = bx - nArgBlk - nTrBlk;
        size_t n8 = ((size_t)V * D) >> 3;                  // groups of 8 floats
        size_t stride = ((size_t)gridDim.x - nArgBlk - nTrBlk) * 256;
        for (size_t i = (size_t)cid * 256 + threadIdx.x; i < n8; i += stride) {
            f32x4 v0 = __builtin_nontemporal_load((const f32x4*)(we + i * 8));
            f32x4 v1 = __builtin_nontemporal_load((const f32x4*)(we + i * 8 + 4));
            __half2 h0 = __float22half2_rn(make_float2(v0.x, v0.y));
            __half2 h1 = __float22half2_rn(make_float2(v0.z, v0.w));
            __half2 h2 = __float22half2_rn(make_float2(v1.x, v1.y));
            __half2 h3 = __float22half2_rn(make_float2(v1.z, v1.w));
            uint4 u;
            u.x = *reinterpret_cast<const unsigned int*>(&h0);
            u.y = *reinterpret_cast<const unsigned int*>(&h1);
            u.z = *reinterpret_cast<const unsigned int*>(&h2);
            u.w = *reinterpret_cast<const unsigned int*>(&h3);
            ((uint4*)weh)[i] = u;              // keep weh cached (gather input)
        }
    }
}

// ---------------------------------------------------------------------------
// K2: per-mention mean embedding + selected score. One wave per mention.
// fp16 table: one wave-load (16B/lane) fetches TWO token rows (512B each):
// lanes 0-31 -> token j, lanes 32-63 -> token j+1; lane pair (c, c+32) holds
// the SAME dims 8c..8c+7, merged by one __shfl_xor(.,32) after the loop.
// men_emb stored fp16 via non-temporal stores (read once later by k_bag).
// ---------------------------------------------------------------------------
__global__ __launch_bounds__(256) void k_mention(const int* __restrict__ fs,
                                                 const int* __restrict__ offs,
                                                 const int* __restrict__ scope,
                                                 const int* __restrict__ type_idx,
                                                 const __half* __restrict__ weh,
                                                 const float* __restrict__ lw,
                                                 __half* __restrict__ men_emb,
                                                 float* __restrict__ sel,
                                                 int M, int T, int B, int D) {
    int wid  = threadIdx.x >> 6;
    int lane = threadIdx.x & 63;
    int m = blockIdx.x * (blockDim.x >> 6) + wid;
    if (m >= M) return;

    int t0 = offs[m];
    int t1 = (m + 1 < M) ? offs[m + 1] : T;
    int c    = lane & 31;      // 16B-chunk (8 dims) within row
    int hsel = lane >> 5;      // 0: even token of pair, 1: odd token

    const float4* we16 = (const float4*)weh;   // 16B = 8 halves; 32 chunks/row
    float a0=0,a1=0,a2=0,a3=0,a4=0,a5=0,a6=0,a7=0;

#define ACC8(q) { const __half2* hh = (const __half2*)&(q);                 \
        float2 f0=__half22float2(hh[0]), f1=__half22float2(hh[1]);          \
        float2 f2=__half22float2(hh[2]), f3=__half22float2(hh[3]);          \
        a0+=f0.x; a1+=f0.y; a2+=f1.x; a3+=f1.y;                             \
        a4+=f2.x; a5+=f2.y; a6+=f3.x; a7+=f3.y; }
#define ACC8S(q,s) { const __half2* hh = (const __half2*)&(q);              \
        float2 f0=__half22float2(hh[0]), f1=__half22float2(hh[1]);          \
        float2 f2=__half22float2(hh[2]), f3=__half22float2(hh[3]);          \
        a0+=(s)*f0.x; a1+=(s)*f0.y; a2+=(s)*f1.x; a3+=(s)*f1.y;             \
        a4+=(s)*f2.x; a5+=(s)*f2.y; a6+=(s)*f3.x; a7+=(s)*f3.y; }

    for (int base = t0; base < t1; base += WAVE) {
        int nn = min(WAVE, t1 - base);
        int myidx = (lane < nn) ? fs[base + lane] : 0;
        int j = 0;
        for (; j + 8 <= nn; j += 8) {          // 4 pair-loads = 8 tokens
            int r0 = __shfl(myidx, j     + hsel);
            int r1 = __shfl(myidx, j + 2 + hsel);
            int r2 = __shfl(myidx, j + 4 + hsel);
            int r3 = __shfl(myidx, j + 6 + hsel);
            float4 q0 = we16[(size_t)r0 * 32 + c];
            float4 q1 = we16[(size_t)r1 * 32 + c];
            float4 q2 = we16[(size_t)r2 * 32 + c];
            float4 q3 = we16[(size_t)r3 * 32 + c];
            ACC8(q0); ACC8(q1); ACC8(q2); ACC8(q3);
        }
        for (; j < nn; j += 2) {               // pair tail (odd via s=0)
            int srcl = j + hsel;
            int rr = __shfl(myidx, (srcl < nn) ? srcl : (nn - 1));
            float s = (srcl < nn) ? 1.0f : 0.0f;
            float4 q = we16[(size_t)rr * 32 + c];
            ACC8S(q, s);
        }
    }

    // merge the two half-wave token streams (lane c and c+32 hold same dims)
    a0 += __shfl_xor(a0, 32); a1 += __shfl_xor(a1, 32);
    a2 += __shfl_xor(a2, 32); a3 += __shfl_xor(a3, 32);
    a4 += __shfl_xor(a4, 32); a5 += __shfl_xor(a5, 32);
    a6 += __shfl_xor(a6, 32); a7 += __shfl_xor(a7, 32);

    float inv = 1.0f / (float)(t1 - t0);
    a0*=inv; a1*=inv; a2*=inv; a3*=inv; a4*=inv; a5*=inv; a6*=inv; a7*=inv;

    // write men_emb fp16 (NT): lanes 0..31 own dims 8c..8c+7 -> 16B per lane
    if (hsel == 0) {
        __half2 p0 = __float22half2_rn(make_float2(a0, a1));
        __half2 p1 = __float22half2_rn(make_float2(a2, a3));
        __half2 p2 = __float22half2_rn(make_float2(a4, a5));
        __half2 p3 = __float22half2_rn(make_float2(a6, a7));
        u32x4 u;
        u.x = *reinterpret_cast<const unsigned int*>(&p0);
        u.y = *reinterpret_cast<const unsigned int*>(&p1);
        u.z = *reinterpret_cast<const unsigned int*>(&p2);
        u.w = *reinterpret_cast<const unsigned int*>(&p3);
        __builtin_nontemporal_store(u, (u32x4*)(men_emb + (size_t)m * D) + c);
    }

    // bag_id: largest b with scope[b] <= m
    int lo = 0, hi = B;
    while (hi - lo > 1) {
        int mid = (lo + hi) >> 1;
        if (scope[mid] <= m) lo = mid; else hi = mid;
    }
    int r = type_idx[lo];

    const float4* wr = (const float4*)(lw + (size_t)r * D);
    float4 u0 = wr[c * 2];
    float4 u1 = wr[c * 2 + 1];
    float p = a0*u0.x + a1*u0.y + a2*u0.z + a3*u0.w
            + a4*u1.x + a5*u1.y + a6*u1.z + a7*u1.w;
    for (int off = 16; off > 0; off >>= 1) p += __shfl_xor(p, off);
    if (lane == 0) sel[m] = p;
}

// ---------------------------------------------------------------------------
// K3: wave per bag. Max-shifted softmax over sel (R4-proven numerics),
// weighted sum of fp16 mention rows via pair-loads (two contiguous rows per
// wave-load; lanes 0-31 row j, 32-63 row j+1; xor-32 merge), projection via
// fp16 W^T (lane kc owns out cols 2kc,2kc+1; wave-private LDS broadcast).
// ---------------------------------------------------------------------------
__global__ __launch_bounds__(256) void k_bag(const int* __restrict__ scope,
                                             const float* __restrict__ sel,
                                             const __half* __restrict__ men_emb,
                                             const __half* __restrict__ wt,
                                             float* __restrict__ out,
                                             int B, int D, int K) {
    __shared__ float s_be[4][256];
    int wid  = threadIdx.x >> 6;
    int lane = threadIdx.x & 63;
    int b = blockIdx.x * (blockDim.x >> 6) + wid;
    if (b >= B) return;

    int m0 = scope[b];
    int m1 = scope[b + 1];
    int n  = m1 - m0;
    int c    = lane & 31;
    int hsel = lane >> 5;

    // ---- softmax stats (butterfly so every lane has them) ----
    float mx = -INFINITY;
    for (int i = lane; i < n; i += WAVE) mx = fmaxf(mx, sel[m0 + i]);
    for (int off = 32; off > 0; off >>= 1) mx = fmaxf(mx, __shfl_xor(mx, off));
    float se = 0.f;
    for (int i = lane; i < n; i += WAVE) se += expf(sel[m0 + i] - mx);
    for (int off = 32; off > 0; off >>= 1) se += __shfl_xor(se, off);
    float inv_se = 1.0f / se;

    // ---- weighted sum of fp16 mention rows (pair-loads) ----
    const float4* me16 = (const float4*)men_emb;   // 32 chunks per 512B row
    float a0=0,a1=0,a2=0,a3=0,a4=0,a5=0,a6=0,a7=0;
    for (int base = 0; base < n; base += WAVE) {
        int nn = min(WAVE, n - base);
        float av = (lane < nn) ? expf(sel[m0 + base + lane] - mx) * inv_se : 0.f;
        int j = 0;
        for (; j + 4 <= nn; j += 4) {              // 2 pair-loads = 4 mentions
            float w0 = __shfl(av, j     + hsel);
            float w1 = __shfl(av, j + 2 + hsel);
            float4 q0 = me16[(size_t)(m0 + base + j     + hsel) * 32 + c];
            float4 q1 = me16[(size_t)(m0 + base + j + 2 + hsel) * 32 + c];
            ACC8S(q0, w0); ACC8S(q1, w1);
        }
        for (; j < nn; j += 2) {                   // pair tail (odd via w=0)
            int srcl = j + hsel;
            int rr = (srcl < nn) ? srcl : (nn - 1);
            float w = __shfl(av, rr) * ((srcl < nn) ? 1.0f : 0.0f);
            float4 q = me16[(size_t)(m0 + base + rr) * 32 + c];
            ACC8S(q, w);
        }
    }
    a0 += __shfl_xor(a0, 32); a1 += __shfl_xor(a1, 32);
    a2 += __shfl_xor(a2, 32); a3 += __shfl_xor(a3, 32);
    a4 += __shfl_xor(a4, 32); a5 += __shfl_xor(a5, 32);
    a6 += __shfl_xor(a6, 32); a7 += __shfl_xor(a7, 32);

    // lanes 0-31 hold bag_emb dims 8c..8c+7 -> wave-private LDS
    float* be = s_be[wid];
    if (hsel == 0) {
        ((float4*)be)[c * 2]     = make_float4(a0, a1, a2, a3);
        ((float4*)be)[c * 2 + 1] = make_float4(a4, a5, a6, a7);
    }

    // ---- projection via fp16 W^T ----
    const __half2* wt2 = (const __half2*)wt;    // [D][KPAD/2] half2
    float2 o = make_float2(0.f, 0.f);
    int kc = lane;                              // half2 column (2kc, 2kc+1)
    #pragma unroll 4
    for (int d4 = 0; d4 < 64; ++d4) {
        float4 b4 = ((const float4*)be)[d4];    // LDS broadcast read
        int d = d4 << 2;
        float2 w0 = __half22float2(wt2[(size_t)(d + 0) * (KPAD/2) + kc]);
        float2 w1 = __half22float2(wt2[(size_t)(d + 1) * (KPAD/2) + kc]);
        float2 w2 = __half22float2(wt2[(size_t)(d + 2) * (KPAD/2) + kc]);
        float2 w3 = __half22float2(wt2[(size_t)(d + 3) * (KPAD/2) + kc]);
        o.x += b4.x*w0.x + b4.y*w1.x + b4.z*w2.x + b4.w*w3.x;
        o.y += b4.x*w0.y + b4.y*w1.y + b4.z*w2.y + b4.w*w3.y;
    }
    int k0 = kc * 2;
    float* ob = out + (size_t)b * K;
    if (k0 + 1 < K) {
        ((float2*)ob)[kc] = o;
    } else if (k0 < K) {
        ob[k0] = o.x;
    }
#undef ACC8
#undef ACC8S
}

// ---------------------------------------------------------------------------
extern "C" void kernel_launch(void* const* d_in, const int* in_sizes, int n_in,
                              void* d_out, int out_size, void* d_ws, size_t ws_size,
                              hipStream_t stream) {
    const int*   feature_seq = (const int*)d_in[0];
    const int*   offset_seq  = (const int*)d_in[1];
    const int*   scope       = (const int*)d_in[2];
    const float* typeTensor  = (const float*)d_in[3];
    const float* word_emb    = (const float*)d_in[4];
    const float* linear_w    = (const float*)d_in[5];
    float* out = (float*)d_out;

    const int T = in_sizes[0];
    const int M = in_sizes[1];
    const int B = in_sizes[2] - 1;
    const int K = in_sizes[3] / B;       // 100
    const int D = in_sizes[5] / K;       // 256
    const int V = in_sizes[4] / D;       // 100000

    // workspace carve-up
    char* w = (char*)d_ws;
    auto align256 = [](size_t x) { return (x + 255) & ~(size_t)255; };
    int*    type_idx = (int*)w;    w += align256((size_t)B * sizeof(int));
    float*  sel      = (float*)w;  w += align256((size_t)M * sizeof(float));
    __half* wt       = (__half*)w; w += align256((size_t)D * KPAD * sizeof(__half));
    __half* weh      = (__half*)w; w += align256((size_t)V * D * sizeof(__half));
    __half* men_emb  = (__half*)w; // M * D halves

    // K1: argmax + WT fp16 transpose + table fp32->fp16 (NT source loads)
    {
        int bagsPerBlock = 256 / WAVE;
        int nArgBlk  = (B + bagsPerBlock - 1) / bagsPerBlock;
        int nTrBlk   = (D * KPAD + 1023) / 1024;
        int nConvBlk = 4096;
        k_prep<<<nArgBlk + nTrBlk + nConvBlk, 256, 0, stream>>>(
            typeTensor, linear_w, word_emb, type_idx, wt, weh,
            B, K, D, V, nArgBlk, nTrBlk);
    }
    // K2: mention means + selected scores (wave per mention, fp16 gather)
    {
        int mentionsPerBlock = 256 / WAVE;
        int grid = (M + mentionsPerBlock - 1) / mentionsPerBlock;
        k_mention<<<grid, 256, 0, stream>>>(feature_seq, offset_seq, scope,
                                            type_idx, weh, linear_w, men_emb,
                                            sel, M, T, B, D);
    }
    // K3: per-bag softmax + weighted sum + projection (wave per bag)
    {
        int bagsPerBlock = 256 / WAVE;
        int grid = (B + bagsPerBlock - 1) / bagsPerBlock;
        k_bag<<<grid, 256, 0, stream>>>(scope, sel, men_emb, wt, out, B, D, K);
    }
}

// Round 9
// 231.935 us; speedup vs baseline: 1.0864x; 1.0528x over previous
//
#include <hip/hip_runtime.h>
#include <hip/hip_fp16.h>
#include <math.h>

#define WAVE 64
#define KPAD 128   // padded K for W^T (zero-filled cols K..127)

typedef float        f32x4 __attribute__((ext_vector_type(4)));
typedef unsigned int u32x4 __attribute__((ext_vector_type(4)));

// fp32 convert-and-accumulate of one 16B chunk (8 halves) into a0..a7
#define ACC8(q) { const __half2* hh = (const __half2*)&(q);                 \
        float2 f0=__half22float2(hh[0]), f1=__half22float2(hh[1]);          \
        float2 f2=__half22float2(hh[2]), f3=__half22float2(hh[3]);          \
        a0+=f0.x; a1+=f0.y; a2+=f1.x; a3+=f1.y;                             \
        a4+=f2.x; a5+=f2.y; a6+=f3.x; a7+=f3.y; }
#define ACC8S(q,s) { const __half2* hh = (const __half2*)&(q);              \
        float2 f0=__half22float2(hh[0]), f1=__half22float2(hh[1]);          \
        float2 f2=__half22float2(hh[2]), f3=__half22float2(hh[3]);          \
        a0+=(s)*f0.x; a1+=(s)*f0.y; a2+=(s)*f1.x; a3+=(s)*f1.y;             \
        a4+=(s)*f2.x; a5+=(s)*f2.y; a6+=(s)*f3.x; a7+=(s)*f3.y; }

// ---------------------------------------------------------------------------
// K1 (prep), grid sections:
//  [0, nArgBlk):       type_idx[b] = argmax_k typeTensor[b*K+k]  (wave/bag)
//  [+, nTrBlk):        WT[d][c] = fp16((c<K) ? W[c][d] : 0)
//  [+, nBagBlk):       bag_id[m] = largest b with scope[b] <= m
//  [+, nConvBlk):      weh = fp16(we)  (grid-strided, NT source loads)
// ---------------------------------------------------------------------------
__global__ __launch_bounds__(256) void k_prep(const float* __restrict__ tt,
                                              const float* __restrict__ lw,
                                              const float* __restrict__ we,
                                              const int* __restrict__ scope,
                                              int* __restrict__ type_idx,
                                              int* __restrict__ bag_id,
                                              __half* __restrict__ wt,
                                              __half* __restrict__ weh,
                                              int B, int K, int D, int V, int M,
                                              int nArgBlk, int nTrBlk, int nBagBlk) {
    int bx = blockIdx.x;
    if (bx < nArgBlk) {
        int wid  = threadIdx.x >> 6;
        int lane = threadIdx.x & 63;
        int b = bx * (blockDim.x >> 6) + wid;
        if (b >= B) return;
        float best = -INFINITY;
        int   bi   = 0x7fffffff;
        for (int k = lane; k < K; k += WAVE) {
            float v = tt[(size_t)b * K + k];
            if (v > best) { best = v; bi = k; }
        }
        for (int off = 32; off > 0; off >>= 1) {
            float ov = __shfl_down(best, off);
            int   oi = __shfl_down(bi, off);
            if (ov > best || (ov == best && oi < bi)) { best = ov; bi = oi; }
        }
        if (lane == 0) type_idx[b] = bi;
    } else if (bx < nArgBlk + nTrBlk) {
        int bid = bx - nArgBlk;
        int base = (bid * 256 + (int)threadIdx.x) * 4;
        int total = D * KPAD;
        for (int i = 0; i < 4; ++i) {
            int e = base + i;
            if (e >= total) break;
            int d = e >> 7;        // / KPAD
            int c = e & (KPAD - 1);
            wt[e] = (c < K) ? __float2half(lw[(size_t)c * D + d]) : __half(0.0f);
        }
    } else if (bx < nArgBlk + nTrBlk + nBagBlk) {
        int m = (bx - nArgBlk - nTrBlk) * 256 + threadIdx.x;
        if (m >= M) return;
        int lo = 0, hi = B;
        while (hi - lo > 1) {
            int mid = (lo + hi) >> 1;
            if (scope[mid] <= m) lo = mid; else hi = mid;
        }
        bag_id[m] = lo;
    } else {
        int cid = bx - nArgBlk - nTrBlk - nBagBlk;
        size_t n8 = ((size_t)V * D) >> 3;                  // groups of 8 floats
        size_t stride = ((size_t)gridDim.x - nArgBlk - nTrBlk - nBagBlk) * 256;
        for (size_t i = (size_t)cid * 256 + threadIdx.x; i < n8; i += stride) {
            f32x4 v0 = __builtin_nontemporal_load((const f32x4*)(we + i * 8));
            f32x4 v1 = __builtin_nontemporal_load((const f32x4*)(we + i * 8 + 4));
            __half2 h0 = __float22half2_rn(make_float2(v0.x, v0.y));
            __half2 h1 = __float22half2_rn(make_float2(v0.z, v0.w));
            __half2 h2 = __float22half2_rn(make_float2(v1.x, v1.y));
            __half2 h3 = __float22half2_rn(make_float2(v1.z, v1.w));
            uint4 u;
            u.x = *reinterpret_cast<const unsigned int*>(&h0);
            u.y = *reinterpret_cast<const unsigned int*>(&h1);
            u.z = *reinterpret_cast<const unsigned int*>(&h2);
            u.w = *reinterpret_cast<const unsigned int*>(&h3);
            ((uint4*)weh)[i] = u;              // keep weh cached (gather input)
        }
    }
}

// ---------------------------------------------------------------------------
// K2: per-mention mean embedding + selected score. One wave per mention.
// fp16 table pair-row loads (lanes 0-31 token j, 32-63 token j+1).
// Depth-2 fp16 add tree (magnitude <= 4 elems, ~3 roundings at eps 2.4e-5:
// numerically safe) then one fp32 convert-add per 8 tokens: 28 VALU vs 64.
// bag_id precomputed in k_prep; W-row/rsel loads hoisted above the loop.
// men_emb stored fp16 via non-temporal stores.
// ---------------------------------------------------------------------------
__global__ __launch_bounds__(256) void k_mention(const int* __restrict__ fs,
                                                 const int* __restrict__ offs,
                                                 const int* __restrict__ bag_id,
                                                 const int* __restrict__ type_idx,
                                                 const __half* __restrict__ weh,
                                                 const float* __restrict__ lw,
                                                 __half* __restrict__ men_emb,
                                                 float* __restrict__ sel,
                                                 int M, int T, int B, int D) {
    int wid  = threadIdx.x >> 6;
    int lane = threadIdx.x & 63;
    int m = blockIdx.x * (blockDim.x >> 6) + wid;
    if (m >= M) return;

    int t0 = offs[m];
    int t1 = (m + 1 < M) ? offs[m + 1] : T;
    int c    = lane & 31;      // 16B-chunk (8 dims) within row
    int hsel = lane >> 5;      // 0: even token of pair, 1: odd token

    // issue epilogue-dependency loads early (hidden under the gather loop)
    int r = type_idx[bag_id[m]];
    const float4* wr = (const float4*)(lw + (size_t)r * D);
    float4 u0 = wr[c * 2];
    float4 u1 = wr[c * 2 + 1];

    const float4* we16 = (const float4*)weh;   // 16B = 8 halves; 32 chunks/row
    float a0=0,a1=0,a2=0,a3=0,a4=0,a5=0,a6=0,a7=0;

    for (int base = t0; base < t1; base += WAVE) {
        int nn = min(WAVE, t1 - base);
        int myidx = (lane < nn) ? fs[base + lane] : 0;
        int j = 0;
        for (; j + 8 <= nn; j += 8) {          // 4 pair-loads = 8 tokens
            int r0 = __shfl(myidx, j     + hsel);
            int r1 = __shfl(myidx, j + 2 + hsel);
            int r2 = __shfl(myidx, j + 4 + hsel);
            int r3 = __shfl(myidx, j + 6 + hsel);
            float4 q0 = we16[(size_t)r0 * 32 + c];
            float4 q1 = we16[(size_t)r1 * 32 + c];
            float4 q2 = we16[(size_t)r2 * 32 + c];
            float4 q3 = we16[(size_t)r3 * 32 + c];
            // depth-2 fp16 tree: (q0+q1) + (q2+q3), then fp32 convert-add
            const __half2* p0 = (const __half2*)&q0;
            const __half2* p1 = (const __half2*)&q1;
            const __half2* p2 = (const __half2*)&q2;
            const __half2* p3 = (const __half2*)&q3;
            __half2 s0 = __hadd2(__hadd2(p0[0], p1[0]), __hadd2(p2[0], p3[0]));
            __half2 s1 = __hadd2(__hadd2(p0[1], p1[1]), __hadd2(p2[1], p3[1]));
            __half2 s2 = __hadd2(__hadd2(p0[2], p1[2]), __hadd2(p2[2], p3[2]));
            __half2 s3 = __hadd2(__hadd2(p0[3], p1[3]), __hadd2(p2[3], p3[3]));
            float2 f0=__half22float2(s0), f1=__half22float2(s1);
            float2 f2=__half22float2(s2), f3=__half22float2(s3);
            a0+=f0.x; a1+=f0.y; a2+=f1.x; a3+=f1.y;
            a4+=f2.x; a5+=f2.y; a6+=f3.x; a7+=f3.y;
        }
        for (; j < nn; j += 2) {               // pair tail (odd via s=0), fp32
            int srcl = j + hsel;
            int rr = __shfl(myidx, (srcl < nn) ? srcl : (nn - 1));
            float s = (srcl < nn) ? 1.0f : 0.0f;
            float4 q = we16[(size_t)rr * 32 + c];
            ACC8S(q, s);
        }
    }

    // merge the two half-wave token streams (lane c and c+32 hold same dims)
    a0 += __shfl_xor(a0, 32); a1 += __shfl_xor(a1, 32);
    a2 += __shfl_xor(a2, 32); a3 += __shfl_xor(a3, 32);
    a4 += __shfl_xor(a4, 32); a5 += __shfl_xor(a5, 32);
    a6 += __shfl_xor(a6, 32); a7 += __shfl_xor(a7, 32);

    float inv = 1.0f / (float)(t1 - t0);
    a0*=inv; a1*=inv; a2*=inv; a3*=inv; a4*=inv; a5*=inv; a6*=inv; a7*=inv;

    // write men_emb fp16 (NT): lanes 0..31 own dims 8c..8c+7 -> 16B per lane
    if (hsel == 0) {
        __half2 p0 = __float22half2_rn(make_float2(a0, a1));
        __half2 p1 = __float22half2_rn(make_float2(a2, a3));
        __half2 p2 = __float22half2_rn(make_float2(a4, a5));
        __half2 p3 = __float22half2_rn(make_float2(a6, a7));
        u32x4 u;
        u.x = *reinterpret_cast<const unsigned int*>(&p0);
        u.y = *reinterpret_cast<const unsigned int*>(&p1);
        u.z = *reinterpret_cast<const unsigned int*>(&p2);
        u.w = *reinterpret_cast<const unsigned int*>(&p3);
        __builtin_nontemporal_store(u, (u32x4*)(men_emb + (size_t)m * D) + c);
    }

    float p = a0*u0.x + a1*u0.y + a2*u0.z + a3*u0.w
            + a4*u1.x + a5*u1.y + a6*u1.z + a7*u1.w;
    for (int off = 16; off > 0; off >>= 1) p += __shfl_xor(p, off);
    if (lane == 0) sel[m] = p;
}

// ---------------------------------------------------------------------------
// K3: wave per bag. Max-shifted softmax over sel, weighted sum of fp16
// mention rows via pair-loads, projection via fp16 W^T (lane kc owns out
// cols 2kc,2kc+1; wave-private LDS broadcast of bag_emb).
// ---------------------------------------------------------------------------
__global__ __launch_bounds__(256) void k_bag(const int* __restrict__ scope,
                                             const float* __restrict__ sel,
                                             const __half* __restrict__ men_emb,
                                             const __half* __restrict__ wt,
                                             float* __restrict__ out,
                                             int B, int D, int K) {
    __shared__ float s_be[4][256];
    int wid  = threadIdx.x >> 6;
    int lane = threadIdx.x & 63;
    int b = blockIdx.x * (blockDim.x >> 6) + wid;
    if (b >= B) return;

    int m0 = scope[b];
    int m1 = scope[b + 1];
    int n  = m1 - m0;
    int c    = lane & 31;
    int hsel = lane >> 5;

    // ---- softmax stats (butterfly so every lane has them) ----
    float mx = -INFINITY;
    for (int i = lane; i < n; i += WAVE) mx = fmaxf(mx, sel[m0 + i]);
    for (int off = 32; off > 0; off >>= 1) mx = fmaxf(mx, __shfl_xor(mx, off));
    float se = 0.f;
    for (int i = lane; i < n; i += WAVE) se += expf(sel[m0 + i] - mx);
    for (int off = 32; off > 0; off >>= 1) se += __shfl_xor(se, off);
    float inv_se = 1.0f / se;

    // ---- weighted sum of fp16 mention rows (pair-loads) ----
    const float4* me16 = (const float4*)men_emb;   // 32 chunks per 512B row
    float a0=0,a1=0,a2=0,a3=0,a4=0,a5=0,a6=0,a7=0;
    for (int base = 0; base < n; base += WAVE) {
        int nn = min(WAVE, n - base);
        float av = (lane < nn) ? expf(sel[m0 + base + lane] - mx) * inv_se : 0.f;
        int j = 0;
        for (; j + 4 <= nn; j += 4) {              // 2 pair-loads = 4 mentions
            float w0 = __shfl(av, j     + hsel);
            float w1 = __shfl(av, j + 2 + hsel);
            float4 q0 = me16[(size_t)(m0 + base + j     + hsel) * 32 + c];
            float4 q1 = me16[(size_t)(m0 + base + j + 2 + hsel) * 32 + c];
            ACC8S(q0, w0); ACC8S(q1, w1);
        }
        for (; j < nn; j += 2) {                   // pair tail (odd via w=0)
            int srcl = j + hsel;
            int rr = (srcl < nn) ? srcl : (nn - 1);
            float w = __shfl(av, rr) * ((srcl < nn) ? 1.0f : 0.0f);
            float4 q = me16[(size_t)(m0 + base + rr) * 32 + c];
            ACC8S(q, w);
        }
    }
    a0 += __shfl_xor(a0, 32); a1 += __shfl_xor(a1, 32);
    a2 += __shfl_xor(a2, 32); a3 += __shfl_xor(a3, 32);
    a4 += __shfl_xor(a4, 32); a5 += __shfl_xor(a5, 32);
    a6 += __shfl_xor(a6, 32); a7 += __shfl_xor(a7, 32);

    // lanes 0-31 hold bag_emb dims 8c..8c+7 -> wave-private LDS
    float* be = s_be[wid];
    if (hsel == 0) {
        ((float4*)be)[c * 2]     = make_float4(a0, a1, a2, a3);
        ((float4*)be)[c * 2 + 1] = make_float4(a4, a5, a6, a7);
    }

    // ---- projection via fp16 W^T ----
    const __half2* wt2 = (const __half2*)wt;    // [D][KPAD/2] half2
    float2 o = make_float2(0.f, 0.f);
    int kc = lane;                              // half2 column (2kc, 2kc+1)
    #pragma unroll 4
    for (int d4 = 0; d4 < 64; ++d4) {
        float4 b4 = ((const float4*)be)[d4];    // LDS broadcast read
        int d = d4 << 2;
        float2 w0 = __half22float2(wt2[(size_t)(d + 0) * (KPAD/2) + kc]);
        float2 w1 = __half22float2(wt2[(size_t)(d + 1) * (KPAD/2) + kc]);
        float2 w2 = __half22float2(wt2[(size_t)(d + 2) * (KPAD/2) + kc]);
        float2 w3 = __half22float2(wt2[(size_t)(d + 3) * (KPAD/2) + kc]);
        o.x += b4.x*w0.x + b4.y*w1.x + b4.z*w2.x + b4.w*w3.x;
        o.y += b4.x*w0.y + b4.y*w1.y + b4.z*w2.y + b4.w*w3.y;
    }
    int k0 = kc * 2;
    float* ob = out + (size_t)b * K;
    if (k0 + 1 < K) {
        ((float2*)ob)[kc] = o;
    } else if (k0 < K) {
        ob[k0] = o.x;
    }
}

// ---------------------------------------------------------------------------
extern "C" void kernel_launch(void* const* d_in, const int* in_sizes, int n_in,
                              void* d_out, int out_size, void* d_ws, size_t ws_size,
                              hipStream_t stream) {
    const int*   feature_seq = (const int*)d_in[0];
    const int*   offset_seq  = (const int*)d_in[1];
    const int*   scope       = (const int*)d_in[2];
    const float* typeTensor  = (const float*)d_in[3];
    const float* word_emb    = (const float*)d_in[4];
    const float* linear_w    = (const float*)d_in[5];
    float* out = (float*)d_out;

    const int T = in_sizes[0];
    const int M = in_sizes[1];
    const int B = in_sizes[2] - 1;
    const int K = in_sizes[3] / B;       // 100
    const int D = in_sizes[5] / K;       // 256
    const int V = in_sizes[4] / D;       // 100000

    // workspace carve-up
    char* w = (char*)d_ws;
    auto align256 = [](size_t x) { return (x + 255) & ~(size_t)255; };
    int*    type_idx = (int*)w;    w += align256((size_t)B * sizeof(int));
    int*    bag_id   = (int*)w;    w += align256((size_t)M * sizeof(int));
    float*  sel      = (float*)w;  w += align256((size_t)M * sizeof(float));
    __half* wt       = (__half*)w; w += align256((size_t)D * KPAD * sizeof(__half));
    __half* weh      = (__half*)w; w += align256((size_t)V * D * sizeof(__half));
    __half* men_emb  = (__half*)w; // M * D halves

    // K1: argmax + WT transpose + bag_id + table fp32->fp16
    {
        int bagsPerBlock = 256 / WAVE;
        int nArgBlk  = (B + bagsPerBlock - 1) / bagsPerBlock;
        int nTrBlk   = (D * KPAD + 1023) / 1024;
        int nBagBlk  = (M + 255) / 256;
        int nConvBlk = 4096;
        k_prep<<<nArgBlk + nTrBlk + nBagBlk + nConvBlk, 256, 0, stream>>>(
            typeTensor, linear_w, word_emb, scope, type_idx, bag_id, wt, weh,
            B, K, D, V, M, nArgBlk, nTrBlk, nBagBlk);
    }
    // K2: mention means + selected scores (wave per mention, fp16 gather)
    {
        int mentionsPerBlock = 256 / WAVE;
        int grid = (M + mentionsPerBlock - 1) / mentionsPerBlock;
        k_mention<<<grid, 256, 0, stream>>>(feature_seq, offset_seq, bag_id,
                                            type_idx, weh, linear_w, men_emb,
                                            sel, M, T, B, D);
    }
    // K3: per-bag softmax + weighted sum + projection (wave per bag)
    {
        int bagsPerBlock = 256 / WAVE;
        int grid = (B + bagsPerBlock - 1) / bagsPerBlock;
        k_bag<<<grid, 256, 0, stream>>>(scope, sel, men_emb, wt, out, B, D, K);
    }
}

// Round 11
// 231.396 us; speedup vs baseline: 1.0889x; 1.0023x over previous
//
#include <hip/hip_runtime.h>
#include <hip/hip_fp16.h>
#include <math.h>

#define WAVE 64
#define KPAD 128   // padded K for W^T (zero-filled cols K..127)

typedef float        f32x4 __attribute__((ext_vector_type(4)));
typedef unsigned int u32x4 __attribute__((ext_vector_type(4)));

// fp32 convert-and-accumulate of one 16B chunk (8 halves) into a0..a7
#define ACC8S(q,s) { const __half2* hh = (const __half2*)&(q);              \
        float2 f0=__half22float2(hh[0]), f1=__half22float2(hh[1]);          \
        float2 f2=__half22float2(hh[2]), f3=__half22float2(hh[3]);          \
        a0+=(s)*f0.x; a1+=(s)*f0.y; a2+=(s)*f1.x; a3+=(s)*f1.y;             \
        a4+=(s)*f2.x; a5+=(s)*f2.y; a6+=(s)*f3.x; a7+=(s)*f3.y; }

// ---------------------------------------------------------------------------
// K1 (prep), grid sections:
//  [0, nArgBlk):       type_idx[b] = argmax_k typeTensor[b*K+k]  (wave/bag)
//  [+, nTrBlk):        WT[d][c] = fp16((c<K) ? W[c][d] : 0)
//  [+, nBagBlk):       bag_id[m] = largest b with scope[b] <= m
//  [+, nConvBlk):      weh = fp16(we)  (grid-strided, NT source loads)
// ---------------------------------------------------------------------------
__global__ __launch_bounds__(256) void k_prep(const float* __restrict__ tt,
                                              const float* __restrict__ lw,
                                              const float* __restrict__ we,
                                              const int* __restrict__ scope,
                                              int* __restrict__ type_idx,
                                              int* __restrict__ bag_id,
                                              __half* __restrict__ wt,
                                              __half* __restrict__ weh,
                                              int B, int K, int D, int V, int M,
                                              int nArgBlk, int nTrBlk, int nBagBlk) {
    int bx = blockIdx.x;
    if (bx < nArgBlk) {
        int wid  = threadIdx.x >> 6;
        int lane = threadIdx.x & 63;
        int b = bx * (blockDim.x >> 6) + wid;
        if (b >= B) return;
        float best = -INFINITY;
        int   bi   = 0x7fffffff;
        for (int k = lane; k < K; k += WAVE) {
            float v = tt[(size_t)b * K + k];
            if (v > best) { best = v; bi = k; }
        }
        for (int off = 32; off > 0; off >>= 1) {
            float ov = __shfl_down(best, off);
            int   oi = __shfl_down(bi, off);
            if (ov > best || (ov == best && oi < bi)) { best = ov; bi = oi; }
        }
        if (lane == 0) type_idx[b] = bi;
    } else if (bx < nArgBlk + nTrBlk) {
        int bid = bx - nArgBlk;
        int base = (bid * 256 + (int)threadIdx.x) * 4;
        int total = D * KPAD;
        for (int i = 0; i < 4; ++i) {
            int e = base + i;
            if (e >= total) break;
            int d = e >> 7;        // / KPAD
            int c = e & (KPAD - 1);
            wt[e] = (c < K) ? __float2half(lw[(size_t)c * D + d]) : __half(0.0f);
        }
    } else if (bx < nArgBlk + nTrBlk + nBagBlk) {
        int m = (bx - nArgBlk - nTrBlk) * 256 + threadIdx.x;
        if (m >= M) return;
        int lo = 0, hi = B;
        while (hi - lo > 1) {
            int mid = (lo + hi) >> 1;
            if (scope[mid] <= m) lo = mid; else hi = mid;
        }
        bag_id[m] = lo;
    } else {
        int cid = bx - nArgBlk - nTrBlk - nBagBlk;
        size_t n8 = ((size_t)V * D) >> 3;                  // groups of 8 floats
        size_t stride = ((size_t)gridDim.x - nArgBlk - nTrBlk - nBagBlk) * 256;
        for (size_t i = (size_t)cid * 256 + threadIdx.x; i < n8; i += stride) {
            f32x4 v0 = __builtin_nontemporal_load((const f32x4*)(we + i * 8));
            f32x4 v1 = __builtin_nontemporal_load((const f32x4*)(we + i * 8 + 4));
            __half2 h0 = __float22half2_rn(make_float2(v0.x, v0.y));
            __half2 h1 = __float22half2_rn(make_float2(v0.z, v0.w));
            __half2 h2 = __float22half2_rn(make_float2(v1.x, v1.y));
            __half2 h3 = __float22half2_rn(make_float2(v1.z, v1.w));
            uint4 u;
            u.x = *reinterpret_cast<const unsigned int*>(&h0);
            u.y = *reinterpret_cast<const unsigned int*>(&h1);
            u.z = *reinterpret_cast<const unsigned int*>(&h2);
            u.w = *reinterpret_cast<const unsigned int*>(&h3);
            ((uint4*)weh)[i] = u;              // keep weh cached (gather input)
        }
    }
}

// ---------------------------------------------------------------------------
// K2: per-mention mean embedding + selected score. One wave per mention.
// fp16 table pair-row loads (lanes 0-31 token j, 32-63 token j+1).
// Depth-2 fp16 add tree (magnitude <= 4 elems, ~3 roundings at eps 2.4e-5:
// numerically safe) then one fp32 convert-add per 8 tokens: 28 VALU vs 64.
// bag_id precomputed in k_prep; W-row/rsel loads hoisted above the loop.
// men_emb stored fp16 via non-temporal stores.
// ---------------------------------------------------------------------------
__global__ __launch_bounds__(256) void k_mention(const int* __restrict__ fs,
                                                 const int* __restrict__ offs,
                                                 const int* __restrict__ bag_id,
                                                 const int* __restrict__ type_idx,
                                                 const __half* __restrict__ weh,
                                                 const float* __restrict__ lw,
                                                 __half* __restrict__ men_emb,
                                                 float* __restrict__ sel,
                                                 int M, int T, int B, int D) {
    int wid  = threadIdx.x >> 6;
    int lane = threadIdx.x & 63;
    int m = blockIdx.x * (blockDim.x >> 6) + wid;
    if (m >= M) return;

    int t0 = offs[m];
    int t1 = (m + 1 < M) ? offs[m + 1] : T;
    int c    = lane & 31;      // 16B-chunk (8 dims) within row
    int hsel = lane >> 5;      // 0: even token of pair, 1: odd token

    // issue epilogue-dependency loads early (hidden under the gather loop)
    int r = type_idx[bag_id[m]];
    const float4* wr = (const float4*)(lw + (size_t)r * D);
    float4 u0 = wr[c * 2];
    float4 u1 = wr[c * 2 + 1];

    const float4* we16 = (const float4*)weh;   // 16B = 8 halves; 32 chunks/row
    float a0=0,a1=0,a2=0,a3=0,a4=0,a5=0,a6=0,a7=0;

    for (int base = t0; base < t1; base += WAVE) {
        int nn = min(WAVE, t1 - base);
        int myidx = (lane < nn) ? fs[base + lane] : 0;
        int j = 0;
        for (; j + 8 <= nn; j += 8) {          // 4 pair-loads = 8 tokens
            int r0 = __shfl(myidx, j     + hsel);
            int r1 = __shfl(myidx, j + 2 + hsel);
            int r2 = __shfl(myidx, j + 4 + hsel);
            int r3 = __shfl(myidx, j + 6 + hsel);
            float4 q0 = we16[(size_t)r0 * 32 + c];
            float4 q1 = we16[(size_t)r1 * 32 + c];
            float4 q2 = we16[(size_t)r2 * 32 + c];
            float4 q3 = we16[(size_t)r3 * 32 + c];
            // depth-2 fp16 tree: (q0+q1) + (q2+q3), then fp32 convert-add
            const __half2* p0 = (const __half2*)&q0;
            const __half2* p1 = (const __half2*)&q1;
            const __half2* p2 = (const __half2*)&q2;
            const __half2* p3 = (const __half2*)&q3;
            __half2 s0 = __hadd2(__hadd2(p0[0], p1[0]), __hadd2(p2[0], p3[0]));
            __half2 s1 = __hadd2(__hadd2(p0[1], p1[1]), __hadd2(p2[1], p3[1]));
            __half2 s2 = __hadd2(__hadd2(p0[2], p1[2]), __hadd2(p2[2], p3[2]));
            __half2 s3 = __hadd2(__hadd2(p0[3], p1[3]), __hadd2(p2[3], p3[3]));
            float2 f0=__half22float2(s0), f1=__half22float2(s1);
            float2 f2=__half22float2(s2), f3=__half22float2(s3);
            a0+=f0.x; a1+=f0.y; a2+=f1.x; a3+=f1.y;
            a4+=f2.x; a5+=f2.y; a6+=f3.x; a7+=f3.y;
        }
        for (; j < nn; j += 2) {               // pair tail (odd via s=0), fp32
            int srcl = j + hsel;
            int rr = __shfl(myidx, (srcl < nn) ? srcl : (nn - 1));
            float s = (srcl < nn) ? 1.0f : 0.0f;
            float4 q = we16[(size_t)rr * 32 + c];
            ACC8S(q, s);
        }
    }

    // merge the two half-wave token streams (lane c and c+32 hold same dims)
    a0 += __shfl_xor(a0, 32); a1 += __shfl_xor(a1, 32);
    a2 += __shfl_xor(a2, 32); a3 += __shfl_xor(a3, 32);
    a4 += __shfl_xor(a4, 32); a5 += __shfl_xor(a5, 32);
    a6 += __shfl_xor(a6, 32); a7 += __shfl_xor(a7, 32);

    float inv = 1.0f / (float)(t1 - t0);
    a0*=inv; a1*=inv; a2*=inv; a3*=inv; a4*=inv; a5*=inv; a6*=inv; a7*=inv;

    // write men_emb fp16 (NT): lanes 0..31 own dims 8c..8c+7 -> 16B per lane
    if (hsel == 0) {
        __half2 p0 = __float22half2_rn(make_float2(a0, a1));
        __half2 p1 = __float22half2_rn(make_float2(a2, a3));
        __half2 p2 = __float22half2_rn(make_float2(a4, a5));
        __half2 p3 = __float22half2_rn(make_float2(a6, a7));
        u32x4 u;
        u.x = *reinterpret_cast<const unsigned int*>(&p0);
        u.y = *reinterpret_cast<const unsigned int*>(&p1);
        u.z = *reinterpret_cast<const unsigned int*>(&p2);
        u.w = *reinterpret_cast<const unsigned int*>(&p3);
        __builtin_nontemporal_store(u, (u32x4*)(men_emb + (size_t)m * D) + c);
    }

    float p = a0*u0.x + a1*u0.y + a2*u0.z + a3*u0.w
            + a4*u1.x + a5*u1.y + a6*u1.z + a7*u1.w;
    for (int off = 16; off > 0; off >>= 1) p += __shfl_xor(p, off);
    if (lane == 0) sel[m] = p;
}

// ---------------------------------------------------------------------------
// K3: wave per bag. Max-shifted softmax over sel, weighted sum of fp16
// mention rows via pair-loads, projection via fp16 W^T (lane kc owns out
// cols 2kc,2kc+1; wave-private LDS broadcast of bag_emb).
// ---------------------------------------------------------------------------
__global__ __launch_bounds__(256) void k_bag(const int* __restrict__ scope,
                                             const float* __restrict__ sel,
                                             const __half* __restrict__ men_emb,
                                             const __half* __restrict__ wt,
                                             float* __restrict__ out,
                                             int B, int D, int K) {
    __shared__ float s_be[4][256];
    int wid  = threadIdx.x >> 6;
    int lane = threadIdx.x & 63;
    int b = blockIdx.x * (blockDim.x >> 6) + wid;
    if (b >= B) return;

    int m0 = scope[b];
    int m1 = scope[b + 1];
    int n  = m1 - m0;
    int c    = lane & 31;
    int hsel = lane >> 5;

    // ---- softmax stats (butterfly so every lane has them) ----
    float mx = -INFINITY;
    for (int i = lane; i < n; i += WAVE) mx = fmaxf(mx, sel[m0 + i]);
    for (int off = 32; off > 0; off >>= 1) mx = fmaxf(mx, __shfl_xor(mx, off));
    float se = 0.f;
    for (int i = lane; i < n; i += WAVE) se += expf(sel[m0 + i] - mx);
    for (int off = 32; off > 0; off >>= 1) se += __shfl_xor(se, off);
    float inv_se = 1.0f / se;

    // ---- weighted sum of fp16 mention rows (pair-loads) ----
    const float4* me16 = (const float4*)men_emb;   // 32 chunks per 512B row
    float a0=0,a1=0,a2=0,a3=0,a4=0,a5=0,a6=0,a7=0;
    for (int base = 0; base < n; base += WAVE) {
        int nn = min(WAVE, n - base);
        float av = (lane < nn) ? expf(sel[m0 + base + lane] - mx) * inv_se : 0.f;
        int j = 0;
        for (; j + 4 <= nn; j += 4) {              // 2 pair-loads = 4 mentions
            float w0 = __shfl(av, j     + hsel);
            float w1 = __shfl(av, j + 2 + hsel);
            float4 q0 = me16[(size_t)(m0 + base + j     + hsel) * 32 + c];
            float4 q1 = me16[(size_t)(m0 + base + j + 2 + hsel) * 32 + c];
            ACC8S(q0, w0); ACC8S(q1, w1);
        }
        for (; j < nn; j += 2) {                   // pair tail (odd via w=0)
            int srcl = j + hsel;
            int rr = (srcl < nn) ? srcl : (nn - 1);
            float w = __shfl(av, rr) * ((srcl < nn) ? 1.0f : 0.0f);
            float4 q = me16[(size_t)(m0 + base + rr) * 32 + c];
            ACC8S(q, w);
        }
    }
    a0 += __shfl_xor(a0, 32); a1 += __shfl_xor(a1, 32);
    a2 += __shfl_xor(a2, 32); a3 += __shfl_xor(a3, 32);
    a4 += __shfl_xor(a4, 32); a5 += __shfl_xor(a5, 32);
    a6 += __shfl_xor(a6, 32); a7 += __shfl_xor(a7, 32);

    // lanes 0-31 hold bag_emb dims 8c..8c+7 -> wave-private LDS
    float* be = s_be[wid];
    if (hsel == 0) {
        ((float4*)be)[c * 2]     = make_float4(a0, a1, a2, a3);
        ((float4*)be)[c * 2 + 1] = make_float4(a4, a5, a6, a7);
    }

    // ---- projection via fp16 W^T ----
    const __half2* wt2 = (const __half2*)wt;    // [D][KPAD/2] half2
    float2 o = make_float2(0.f, 0.f);
    int kc = lane;                              // half2 column (2kc, 2kc+1)
    #pragma unroll 4
    for (int d4 = 0; d4 < 64; ++d4) {
        float4 b4 = ((const float4*)be)[d4];    // LDS broadcast read
        int d = d4 << 2;
        float2 w0 = __half22float2(wt2[(size_t)(d + 0) * (KPAD/2) + kc]);
        float2 w1 = __half22float2(wt2[(size_t)(d + 1) * (KPAD/2) + kc]);
        float2 w2 = __half22float2(wt2[(size_t)(d + 2) * (KPAD/2) + kc]);
        float2 w3 = __half22float2(wt2[(size_t)(d + 3) * (KPAD/2) + kc]);
        o.x += b4.x*w0.x + b4.y*w1.x + b4.z*w2.x + b4.w*w3.x;
        o.y += b4.x*w0.y + b4.y*w1.y + b4.z*w2.y + b4.w*w3.y;
    }
    int k0 = kc * 2;
    float* ob = out + (size_t)b * K;
    if (k0 + 1 < K) {
        ((float2*)ob)[kc] = o;
    } else if (k0 < K) {
        ob[k0] = o.x;
    }
}

// ---------------------------------------------------------------------------
extern "C" void kernel_launch(void* const* d_in, const int* in_sizes, int n_in,
                              void* d_out, int out_size, void* d_ws, size_t ws_size,
                              hipStream_t stream) {
    const int*   feature_seq = (const int*)d_in[0];
    const int*   offset_seq  = (const int*)d_in[1];
    const int*   scope       = (const int*)d_in[2];
    const float* typeTensor  = (const float*)d_in[3];
    const float* word_emb    = (const float*)d_in[4];
    const float* linear_w    = (const float*)d_in[5];
    float* out = (float*)d_out;

    const int T = in_sizes[0];
    const int M = in_sizes[1];
    const int B = in_sizes[2] - 1;
    const int K = in_sizes[3] / B;       // 100
    const int D = in_sizes[5] / K;       // 256
    const int V = in_sizes[4] / D;       // 100000

    // workspace carve-up
    char* w = (char*)d_ws;
    auto align256 = [](size_t x) { return (x + 255) & ~(size_t)255; };
    int*    type_idx = (int*)w;    w += align256((size_t)B * sizeof(int));
    int*    bag_id   = (int*)w;    w += align256((size_t)M * sizeof(int));
    float*  sel      = (float*)w;  w += align256((size_t)M * sizeof(float));
    __half* wt       = (__half*)w; w += align256((size_t)D * KPAD * sizeof(__half));
    __half* weh      = (__half*)w; w += align256((size_t)V * D * sizeof(__half));
    __half* men_emb  = (__half*)w; // M * D halves

    // K1: argmax + WT transpose + bag_id + table fp32->fp16
    {
        int bagsPerBlock = 256 / WAVE;
        int nArgBlk  = (B + bagsPerBlock - 1) / bagsPerBlock;
        int nTrBlk   = (D * KPAD + 1023) / 1024;
        int nBagBlk  = (M + 255) / 256;
        int nConvBlk = 4096;
        k_prep<<<nArgBlk + nTrBlk + nBagBlk + nConvBlk, 256, 0, stream>>>(
            typeTensor, linear_w, word_emb, scope, type_idx, bag_id, wt, weh,
            B, K, D, V, M, nArgBlk, nTrBlk, nBagBlk);
    }
    // K2: mention means + selected scores (wave per mention, fp16 gather)
    {
        int mentionsPerBlock = 256 / WAVE;
        int grid = (M + mentionsPerBlock - 1) / mentionsPerBlock;
        k_mention<<<grid, 256, 0, stream>>>(feature_seq, offset_seq, bag_id,
                                            type_idx, weh, linear_w, men_emb,
                                            sel, M, T, B, D);
    }
    // K3: per-bag softmax + weighted sum + projection (wave per bag)
    {
        int bagsPerBlock = 256 / WAVE;
        int grid = (B + bagsPerBlock - 1) / bagsPerBlock;
        k_bag<<<grid, 256, 0, stream>>>(scope, sel, men_emb, wt, out, B, D, K);
    }
}